// Round 1
// baseline (104.957 us; speedup 1.0000x reference)
//
#include <hip/hip_runtime.h>
#include <math.h>

// Positions per layer (B * g * g * 3)
#define NPOS0 1200
#define NPOS1 4800
#define NPOS2 19200
#define BLK0 5     // ceil(1200/256)
#define BLK1 19    // ceil(4800/256)
#define BLK2 75    // 19200/256
#define NBLK (BLK0 + BLK1 + BLK2)

// Per-(layer,batch) compacted-target capacities (expected counts ~6/24/96)
#define CAP0 64
#define CAP1 256
#define CAP2 1024
// slot bases: l0: b*64 ; l1: 256 + b*256 ; l2: 1280 + b*1024 ; total 5376 slots

__device__ __forceinline__ float bce_f(float label, float logit) {
    // max(x,0) - x*l + log1p(exp(-|x|))
    return fmaxf(logit, 0.0f) - logit * label + log1pf(expf(-fabsf(logit)));
}

__global__ __launch_bounds__(256) void k_compact(
    const float* __restrict__ t0, const float* __restrict__ t1, const float* __restrict__ t2,
    int* __restrict__ counts, float4* __restrict__ boxes)
{
    int blk = blockIdx.x;
    const float* t; int l, base, N, P, cap;
    if (blk < BLK0)             { l = 0; base = 0;          N = NPOS0; t = t0; P = 300;  cap = CAP0; }
    else if (blk < BLK0 + BLK1) { l = 1; base = BLK0;       N = NPOS1; t = t1; P = 1200; cap = CAP1; }
    else                        { l = 2; base = BLK0 + BLK1; N = NPOS2; t = t2; P = 4800; cap = CAP2; }
    int idx = (blk - base) * 256 + threadIdx.x;
    if (idx >= N) return;
    const float* tp = t + (size_t)idx * 85;
    float obj = tp[4];
    if (obj != 0.0f) {
        int b = idx / P;
        int slotBase = (l == 0) ? b * CAP0
                     : (l == 1) ? 4 * CAP0 + b * CAP1
                                : 4 * CAP0 + 4 * CAP1 + b * CAP2;
        int s = atomicAdd(&counts[l * 4 + b], 1);
        if (s < cap) {
            boxes[slotBase + s] = make_float4(tp[0], tp[1], tp[2], tp[3]);
        }
    }
}

__global__ __launch_bounds__(256) void k_loss(
    const float* __restrict__ t0, const float* __restrict__ y0,
    const float* __restrict__ t1, const float* __restrict__ y1,
    const float* __restrict__ t2, const float* __restrict__ y2,
    const int* __restrict__ counts, const float4* __restrict__ boxes,
    float* __restrict__ out)
{
    int blk = blockIdx.x;
    const float* t; const float* y; int l, base, N, P, g, cap;
    if (blk < BLK0)             { l = 0; base = 0;          N = NPOS0; t = t0; y = y0; P = 300;  g = 10; cap = CAP0; }
    else if (blk < BLK0 + BLK1) { l = 1; base = BLK0;       N = NPOS1; t = t1; y = y1; P = 1200; g = 20; cap = CAP1; }
    else                        { l = 2; base = BLK0 + BLK1; N = NPOS2; t = t2; y = y2; P = 4800; g = 40; cap = CAP2; }
    int idx = (blk - base) * 256 + threadIdx.x;

    float contrib = 0.0f;
    if (idx < N) {
        int b = idx / P;
        int p = idx - b * P;
        int a = p % 3;
        int cell = p / 3;
        int j = cell % g;      // x-coordinate of grid cell
        int i = cell / g;      // y-coordinate
        float aw, ah;
        if (l == 0)      { aw = (a==0)?116.f:(a==1)?156.f:373.f; ah = (a==0)?90.f:(a==1)?198.f:326.f; }
        else if (l == 1) { aw = (a==0)?30.f :(a==1)?62.f :59.f;  ah = (a==0)?61.f:(a==1)?45.f :119.f; }
        else             { aw = (a==0)?10.f :(a==1)?16.f :33.f;  ah = (a==0)?13.f:(a==1)?30.f :23.f;  }

        const float* tp = t + (size_t)idx * 85;
        const float* yp = y + (size_t)idx * 85;
        float obj = tp[4];
        float q0 = yp[0], q1 = yp[1], q2 = yp[2], q3 = yp[3], q4 = yp[4];
        float gi = (float)g;

        if (obj != 0.0f) {
            // positive position: xy + wh + conf(obj=1) + cls; ignore-mask irrelevant
            float tx = tp[0], ty = tp[1], tw = tp[2], th = tp[3];
            float bs = 2.0f - tw * th;
            float rx = tx * gi - (float)j;
            float ry = ty * gi - (float)i;
            float acc = bs * (bce_f(rx, q0) + bce_f(ry, q1));
            float rw = logf(tw * 320.0f / aw);
            float rh = logf(th * 320.0f / ah);
            float dw = rw - q2, dh = rh - q3;
            acc += bs * 0.5f * (dw * dw + dh * dh);
            acc += bce_f(1.0f, q4);
            float cl = 0.0f;
            #pragma unroll 8
            for (int c = 5; c < 85; ++c) cl += bce_f(tp[c], yp[c]);
            contrib = acc + cl;
        } else {
            // negative position: conf term gated by ignore = (best_iou < 0.5)
            float px = (1.0f / (1.0f + expf(-q0)) + (float)j) / gi;
            float py = (1.0f / (1.0f + expf(-q1)) + (float)i) / gi;
            float pw = expf(q2) * aw / 320.0f;
            float ph = expf(q3) * ah / 320.0f;
            float phx = pw * 0.5f, phy = ph * 0.5f;
            float pminx = px - phx, pmaxx = px + phx;
            float pminy = py - phy, pmaxy = py + phy;
            float parea = pw * ph;

            int cnt = counts[l * 4 + b];
            if (cnt > cap) cnt = cap;
            int slotBase = (l == 0) ? b * CAP0
                         : (l == 1) ? 4 * CAP0 + b * CAP1
                                    : 4 * CAP0 + 4 * CAP1 + b * CAP2;
            const float4* bp = boxes + slotBase;
            float best = -INFINITY;
            for (int k = 0; k < cnt; ++k) {
                float4 tb = bp[k];
                float thx = tb.z * 0.5f, thy = tb.w * 0.5f;
                float wx = fminf(pmaxx, tb.x + thx) - fmaxf(pminx, tb.x - thx);
                float wy = fminf(pmaxy, tb.y + thy) - fmaxf(pminy, tb.y - thy);
                wx = fmaxf(wx, 0.0f);
                wy = fmaxf(wy, 0.0f);
                float inter = wx * wy;
                float iou = inter / (parea + tb.z * tb.w - inter);
                best = fmaxf(best, iou);
            }
            float ignore = (best < 0.5f) ? 1.0f : 0.0f;
            // bce(label=0, logit=q4)
            contrib = ignore * (fmaxf(q4, 0.0f) + log1pf(expf(-fabsf(q4))));
        }
    }

    // block reduction: wave64 shuffle then LDS
    float v = contrib;
    #pragma unroll
    for (int o = 32; o > 0; o >>= 1) v += __shfl_down(v, o, 64);
    __shared__ float red[4];
    int lane = threadIdx.x & 63;
    int w = threadIdx.x >> 6;
    if (lane == 0) red[w] = v;
    __syncthreads();
    if (threadIdx.x == 0) {
        float s = (red[0] + red[1]) + (red[2] + red[3]);
        atomicAdd(out, s * 0.25f);   // mean over batch (B=4), summed over layers
    }
}

extern "C" void kernel_launch(void* const* d_in, const int* in_sizes, int n_in,
                              void* d_out, int out_size, void* d_ws, size_t ws_size,
                              hipStream_t stream) {
    // setup_inputs dict order: t0, y0, t1, y1, t2, y2
    const float* t0 = (const float*)d_in[0];
    const float* y0 = (const float*)d_in[1];
    const float* t1 = (const float*)d_in[2];
    const float* y1 = (const float*)d_in[3];
    const float* t2 = (const float*)d_in[4];
    const float* y2 = (const float*)d_in[5];

    int* counts   = (int*)d_ws;                        // 12 ints
    float4* boxes = (float4*)((char*)d_ws + 64);       // 5376 float4 slots (~86 KB)

    hipMemsetAsync(d_out, 0, sizeof(float), stream);
    hipMemsetAsync(d_ws, 0, 48, stream);               // zero the 12 counters

    k_compact<<<NBLK, 256, 0, stream>>>(t0, t1, t2, counts, boxes);
    k_loss<<<NBLK, 256, 0, stream>>>(t0, y0, t1, y1, t2, y2, counts, boxes, (float*)d_out);
}

// Round 2
// 44.785 us; speedup vs baseline: 2.3436x; 2.3436x over previous
//
#include <hip/hip_runtime.h>
#include <math.h>

// ---- problem constants ----
// layers: g=10/20/40, B=4, 3 anchors, 85 ch. Positions/layer: 1200/4800/19200.
#define CAP0 32
#define CAP1 128
#define CAP2 512
#define POSCAP 2048
// box slot bases: l0: b*CAP0 ; l1: 4*CAP0 + b*CAP1 ; l2: 4*CAP0+4*CAP1 + b*CAP2
// ws layout: [0..64) int counts[16] (12 per-(l,b) counts + counts[12]=posCount)
//            [64 .. 64+2688*16) float4 boxes
//            [43072 .. 43072+POSCAP*4) int posIdx

__device__ __constant__ float c_anc[3][3][2] = {
  {{116.f, 90.f}, {156.f, 198.f}, {373.f, 326.f}},
  {{ 30.f, 61.f}, { 62.f,  45.f}, { 59.f, 119.f}},
  {{ 10.f, 13.f}, { 16.f,  30.f}, { 33.f,  23.f}}};

__device__ __forceinline__ float bce_f(float label, float logit) {
    return fmaxf(logit, 0.0f) - logit * label + log1pf(expf(-fabsf(logit)));
}

__global__ void k_init(int* __restrict__ counts, float* __restrict__ out) {
    int tid = threadIdx.x;
    if (tid < 16) counts[tid] = 0;
    if (tid == 16) out[0] = 0.0f;
}

__global__ __launch_bounds__(64) void k_compact(
    const float* __restrict__ t0, const float* __restrict__ t1, const float* __restrict__ t2,
    int* __restrict__ counts, float4* __restrict__ boxes, int* __restrict__ posIdx)
{
    int flat = blockIdx.x * 64 + threadIdx.x;
    if (flat >= 25200) return;
    int l, idx, P, cap;
    const float* t;
    if (flat < 1200)      { l = 0; idx = flat;        t = t0; P = 300;  cap = CAP0; }
    else if (flat < 6000) { l = 1; idx = flat - 1200; t = t1; P = 1200; cap = CAP1; }
    else                  { l = 2; idx = flat - 6000; t = t2; P = 4800; cap = CAP2; }
    const float* tp = t + (size_t)idx * 85;
    if (tp[4] != 0.0f) {
        int b = idx / P;
        int slotBase = (l == 0) ? b * CAP0
                     : (l == 1) ? 4 * CAP0 + b * CAP1
                                : 4 * CAP0 + 4 * CAP1 + b * CAP2;
        int s = atomicAdd(&counts[l * 4 + b], 1);
        if (s < cap) boxes[slotBase + s] = make_float4(tp[0], tp[1], tp[2], tp[3]);
        int sp = atomicAdd(&counts[12], 1);
        if (sp < POSCAP) posIdx[sp] = (l << 16) | idx;
    }
}

// conf term for ALL positions, uniform control flow; IoU loop from LDS, unrolled x8
__global__ __launch_bounds__(64) void k_neg(
    const float* __restrict__ t0, const float* __restrict__ y0,
    const float* __restrict__ t1, const float* __restrict__ y1,
    const float* __restrict__ t2, const float* __restrict__ y2,
    const int* __restrict__ counts, const float4* __restrict__ boxes,
    float* __restrict__ out)
{
    __shared__ float4 sbox[CAP2];
    int blk = blockIdx.x;
    int l, img, chunk, P, g, cap;
    const float *t, *y;
    if (blk < 20)      { l = 0; img = blk / 5;  chunk = blk % 5;  P = 300;  g = 10; cap = CAP0; t = t0; y = y0; }
    else if (blk < 96) { int r = blk - 20; l = 1; img = r / 19; chunk = r % 19; P = 1200; g = 20; cap = CAP1; t = t1; y = y1; }
    else               { int r = blk - 96; l = 2; img = r / 75; chunk = r % 75; P = 4800; g = 40; cap = CAP2; t = t2; y = y2; }

    int slotBase = (l == 0) ? img * CAP0
                 : (l == 1) ? 4 * CAP0 + img * CAP1
                            : 4 * CAP0 + 4 * CAP1 + img * CAP2;
    int cnt = counts[l * 4 + img];
    if (cnt > cap) cnt = cap;
    int cntPad = (cnt + 7) & ~7;           // zero-pad: iou(pad)=0, doesn't change ignore
    for (int k = threadIdx.x; k < cntPad; k += 64)
        sbox[k] = (k < cnt) ? boxes[slotBase + k] : make_float4(0.f, 0.f, 0.f, 0.f);
    __syncthreads();

    int pos = chunk * 64 + threadIdx.x;
    float contrib = 0.0f;
    if (pos < P) {
        int idx = img * P + pos;
        int a = pos % 3, cell = pos / 3;
        int j = cell % g, i = cell / g;
        float aw = c_anc[l][a][0], ah = c_anc[l][a][1];
        const float* yp = y + (size_t)idx * 85;
        float obj = t[(size_t)idx * 85 + 4];
        float q0 = yp[0], q1 = yp[1], q2 = yp[2], q3 = yp[3], q4 = yp[4];
        float gi = (float)g;

        float px = (1.0f / (1.0f + expf(-q0)) + (float)j) / gi;
        float py = (1.0f / (1.0f + expf(-q1)) + (float)i) / gi;
        float pw = expf(q2) * aw * (1.0f / 320.0f);
        float ph = expf(q3) * ah * (1.0f / 320.0f);
        float phx = pw * 0.5f, phy = ph * 0.5f;
        float pminx = px - phx, pmaxx = px + phx;
        float pminy = py - phy, pmaxy = py + phy;
        float parea = pw * ph;

        float best = -INFINITY;
        for (int k0 = 0; k0 < cntPad; k0 += 8) {
            #pragma unroll
            for (int u = 0; u < 8; ++u) {
                float4 tb = sbox[k0 + u];
                float thx = tb.z * 0.5f, thy = tb.w * 0.5f;
                float wx = fminf(pmaxx, tb.x + thx) - fmaxf(pminx, tb.x - thx);
                float wy = fminf(pmaxy, tb.y + thy) - fmaxf(pminy, tb.y - thy);
                wx = fmaxf(wx, 0.0f);
                wy = fmaxf(wy, 0.0f);
                float inter = wx * wy;
                float iou = inter / (parea + tb.z * tb.w - inter);
                best = fmaxf(best, iou);
            }
        }
        float ignore = (best < 0.5f) ? 1.0f : 0.0f;
        float bce_c = fmaxf(q4, 0.0f) - q4 * obj + log1pf(expf(-fabsf(q4)));
        contrib = (obj + (1.0f - obj) * ignore) * bce_c;   // == ref conf_loss
    }

    float v = contrib;
    #pragma unroll
    for (int o = 32; o > 0; o >>= 1) v += __shfl_down(v, o, 64);
    if (threadIdx.x == 0) atomicAdd(out, v * 0.25f);
}

// one wave per positive: lanes = channels (coalesced); xy/wh/cls + nothing else
__global__ __launch_bounds__(256) void k_pos(
    const float* __restrict__ t0, const float* __restrict__ y0,
    const float* __restrict__ t1, const float* __restrict__ y1,
    const float* __restrict__ t2, const float* __restrict__ y2,
    const int* __restrict__ counts, const int* __restrict__ posIdx,
    float* __restrict__ out)
{
    int gwave = (blockIdx.x * 256 + threadIdx.x) >> 6;
    int lane = threadIdx.x & 63;
    int nPos = counts[12];
    if (nPos > POSCAP) nPos = POSCAP;

    for (int p = gwave; p < nPos; p += 512) {
        int e = posIdx[p];
        int l = e >> 16, idx = e & 0xFFFF;
        const float *t, *y; int P, g;
        if (l == 0)      { t = t0; y = y0; P = 300;  g = 10; }
        else if (l == 1) { t = t1; y = y1; P = 1200; g = 20; }
        else             { t = t2; y = y2; P = 4800; g = 40; }
        int b = idx / P, pos = idx - b * P;
        int a = pos % 3, cell = pos / 3;
        int j = cell % g, i = cell / g;
        float aw = c_anc[l][a][0], ah = c_anc[l][a][1];

        const float* tp = t + (size_t)idx * 85;
        const float* yp = y + (size_t)idx * 85;
        float tv1 = tp[lane], yv1 = yp[lane];       // channels 0..63 (coalesced)
        int c2 = lane + 64;
        float tv2 = 0.f, yv2 = 0.f;
        bool has2 = (c2 < 85);
        if (has2) { tv2 = tp[c2]; yv2 = yp[c2]; }   // channels 64..84

        float tw = __shfl(tv1, 2, 64);
        float th = __shfl(tv1, 3, 64);
        float bs = 2.0f - tw * th;                  // box_scale

        float term;
        if (lane == 0)      term = bs * bce_f(tv1 * (float)g - (float)j, yv1);
        else if (lane == 1) term = bs * bce_f(tv1 * (float)g - (float)i, yv1);
        else if (lane == 2) { float d = logf(tv1 * 320.0f / aw) - yv1; term = bs * 0.5f * d * d; }
        else if (lane == 3) { float d = logf(tv1 * 320.0f / ah) - yv1; term = bs * 0.5f * d * d; }
        else if (lane == 4) term = bce_f(1.0f, yv1);      // conf handled in k_neg gate? no: obj=1 path here
        else                term = bce_f(tv1, yv1);       // cls 5..63
        if (has2) term += bce_f(tv2, yv2);                // cls 64..84

        // NOTE: conf term for positives is ALREADY added by k_neg (gate=1 there),
        // so exclude it here to avoid double count:
        if (lane == 4) term -= bce_f(1.0f, yv1);

        float v = term;
        #pragma unroll
        for (int o = 32; o > 0; o >>= 1) v += __shfl_down(v, o, 64);
        if (lane == 0) atomicAdd(out, v * 0.25f);
    }
}

extern "C" void kernel_launch(void* const* d_in, const int* in_sizes, int n_in,
                              void* d_out, int out_size, void* d_ws, size_t ws_size,
                              hipStream_t stream) {
    // setup_inputs dict order: t0, y0, t1, y1, t2, y2
    const float* t0 = (const float*)d_in[0];
    const float* y0 = (const float*)d_in[1];
    const float* t1 = (const float*)d_in[2];
    const float* y1 = (const float*)d_in[3];
    const float* t2 = (const float*)d_in[4];
    const float* y2 = (const float*)d_in[5];

    int*    counts = (int*)d_ws;
    float4* boxes  = (float4*)((char*)d_ws + 64);
    int*    posIdx = (int*)((char*)d_ws + 64 + 2688 * 16);
    float*  out    = (float*)d_out;

    k_init<<<1, 64, 0, stream>>>(counts, out);
    k_compact<<<394, 64, 0, stream>>>(t0, t1, t2, counts, boxes, posIdx);
    k_neg<<<396, 64, 0, stream>>>(t0, y0, t1, y1, t2, y2, counts, boxes, out);
    k_pos<<<128, 256, 0, stream>>>(t0, y0, t1, y1, t2, y2, counts, posIdx, out);
}

// Round 3
// 31.980 us; speedup vs baseline: 3.2820x; 1.4004x over previous
//
#include <hip/hip_runtime.h>
#include <math.h>

// layers: g=10/20/40, B=4, 3 anchors, 85 ch. Positions/layer: 1200/4800/19200.
#define CAP0 32
#define CAP1 128
#define CAP2 512
#define POSCAP 2048
#define NEG_BLOCKS 396            // l0: 20, l1: 76, l2: 300
#define POS_BLOCKS 256
#define NBLK (NEG_BLOCKS + POS_BLOCKS)   // 652
// ws layout:
//   [0..64)                 int counts[16]  (12 per-(l,b) + counts[12]=posCount)
//   [64 .. 64+2688*16)      float4 boxes
//   [43072 .. 43072+8192)   int posIdx[POSCAP]
//   [51264 .. 51264+NBLK*4) float partials[NBLK]

__device__ __constant__ float c_anc[3][3][2] = {
  {{116.f, 90.f}, {156.f, 198.f}, {373.f, 326.f}},
  {{ 30.f, 61.f}, { 62.f,  45.f}, { 59.f, 119.f}},
  {{ 10.f, 13.f}, { 16.f,  30.f}, { 33.f,  23.f}}};

__device__ __forceinline__ float bce_f(float label, float logit) {
    return fmaxf(logit, 0.0f) - logit * label + log1pf(expf(-fabsf(logit)));
}

__global__ void k_init(int* __restrict__ counts) {
    if (threadIdx.x < 16) counts[threadIdx.x] = 0;
}

__global__ __launch_bounds__(64) void k_compact(
    const float* __restrict__ t0, const float* __restrict__ t1, const float* __restrict__ t2,
    int* __restrict__ counts, float4* __restrict__ boxes, int* __restrict__ posIdx)
{
    int flat = blockIdx.x * 64 + threadIdx.x;
    if (flat >= 25200) return;
    int l, idx, P, cap;
    const float* t;
    if (flat < 1200)      { l = 0; idx = flat;        t = t0; P = 300;  cap = CAP0; }
    else if (flat < 6000) { l = 1; idx = flat - 1200; t = t1; P = 1200; cap = CAP1; }
    else                  { l = 2; idx = flat - 6000; t = t2; P = 4800; cap = CAP2; }
    const float* tp = t + (size_t)idx * 85;
    if (tp[4] != 0.0f) {
        int b = idx / P;
        int slotBase = (l == 0) ? b * CAP0
                     : (l == 1) ? 4 * CAP0 + b * CAP1
                                : 4 * CAP0 + 4 * CAP1 + b * CAP2;
        int s = atomicAdd(&counts[l * 4 + b], 1);
        if (s < cap) boxes[slotBase + s] = make_float4(tp[0], tp[1], tp[2], tp[3]);
        int sp = atomicAdd(&counts[12], 1);
        if (sp < POSCAP) posIdx[sp] = (l << 16) | idx;
    }
}

// blocks [0,396): conf term for all positions (uniform flow, LDS-staged IoU)
// blocks [396,652): positive xy/wh/cls terms, one wave per positive (grid-stride)
// every block writes exactly one partials slot (no global same-address atomics)
__global__ __launch_bounds__(64) void k_main(
    const float* __restrict__ t0, const float* __restrict__ y0,
    const float* __restrict__ t1, const float* __restrict__ y1,
    const float* __restrict__ t2, const float* __restrict__ y2,
    const int* __restrict__ counts, const float4* __restrict__ boxes,
    const int* __restrict__ posIdx, float* __restrict__ partials)
{
    int blk = blockIdx.x;
    float acc = 0.0f;   // per-lane accumulator

    if (blk < NEG_BLOCKS) {
        __shared__ float4 sbox[CAP2];
        int l, img, chunk, P, g, cap;
        const float *t, *y;
        if (blk < 20)      { l = 0; img = blk / 5;  chunk = blk % 5;  P = 300;  g = 10; cap = CAP0; t = t0; y = y0; }
        else if (blk < 96) { int r = blk - 20; l = 1; img = r / 19; chunk = r % 19; P = 1200; g = 20; cap = CAP1; t = t1; y = y1; }
        else               { int r = blk - 96; l = 2; img = r / 75; chunk = r % 75; P = 4800; g = 40; cap = CAP2; t = t2; y = y2; }

        int slotBase = (l == 0) ? img * CAP0
                     : (l == 1) ? 4 * CAP0 + img * CAP1
                                : 4 * CAP0 + 4 * CAP1 + img * CAP2;
        int cnt = counts[l * 4 + img];
        if (cnt > cap) cnt = cap;
        int cntPad = (cnt + 7) & ~7;
        for (int k = threadIdx.x; k < cntPad; k += 64)
            sbox[k] = (k < cnt) ? boxes[slotBase + k] : make_float4(0.f, 0.f, 0.f, 0.f);
        __syncthreads();

        int pos = chunk * 64 + threadIdx.x;
        if (pos < P) {
            int idx = img * P + pos;
            int a = pos % 3, cell = pos / 3;
            int j = cell % g, i = cell / g;
            float aw = c_anc[l][a][0], ah = c_anc[l][a][1];
            const float* yp = y + (size_t)idx * 85;
            float obj = t[(size_t)idx * 85 + 4];
            float q0 = yp[0], q1 = yp[1], q2 = yp[2], q3 = yp[3], q4 = yp[4];
            float gi = (float)g;

            float px = (1.0f / (1.0f + expf(-q0)) + (float)j) / gi;
            float py = (1.0f / (1.0f + expf(-q1)) + (float)i) / gi;
            float pw = expf(q2) * aw * (1.0f / 320.0f);
            float ph = expf(q3) * ah * (1.0f / 320.0f);
            float phx = pw * 0.5f, phy = ph * 0.5f;
            float pminx = px - phx, pmaxx = px + phx;
            float pminy = py - phy, pmaxy = py + phy;
            float parea = pw * ph;

            float best = -INFINITY;
            for (int k0 = 0; k0 < cntPad; k0 += 8) {
                #pragma unroll
                for (int u = 0; u < 8; ++u) {
                    float4 tb = sbox[k0 + u];
                    float thx = tb.z * 0.5f, thy = tb.w * 0.5f;
                    float wx = fminf(pmaxx, tb.x + thx) - fmaxf(pminx, tb.x - thx);
                    float wy = fminf(pmaxy, tb.y + thy) - fmaxf(pminy, tb.y - thy);
                    wx = fmaxf(wx, 0.0f);
                    wy = fmaxf(wy, 0.0f);
                    float inter = wx * wy;
                    float iou = inter / (parea + tb.z * tb.w - inter);
                    best = fmaxf(best, iou);
                }
            }
            float ignore = (best < 0.5f) ? 1.0f : 0.0f;
            float bce_c = fmaxf(q4, 0.0f) - q4 * obj + log1pf(expf(-fabsf(q4)));
            acc = (obj + (1.0f - obj) * ignore) * bce_c;
        }
    } else {
        // positive path: one wave per block; grid-stride over compacted positives
        int lane = threadIdx.x;        // 0..63
        int w = blk - NEG_BLOCKS;      // 0..255
        int nPos = counts[12];
        if (nPos > POSCAP) nPos = POSCAP;
        for (int p = w; p < nPos; p += POS_BLOCKS) {
            int e = posIdx[p];
            int l = e >> 16, idx = e & 0xFFFF;
            const float *t, *y; int P, g;
            if (l == 0)      { t = t0; y = y0; P = 300;  g = 10; }
            else if (l == 1) { t = t1; y = y1; P = 1200; g = 20; }
            else             { t = t2; y = y2; P = 4800; g = 40; }
            int b = idx / P, pos = idx - b * P;
            int a = pos % 3, cell = pos / 3;
            int j = cell % g, i = cell / g;
            float aw = c_anc[l][a][0], ah = c_anc[l][a][1];

            const float* tp = t + (size_t)idx * 85;
            const float* yp = y + (size_t)idx * 85;
            float tv1 = tp[lane], yv1 = yp[lane];        // ch 0..63 (coalesced)
            int c2 = lane + 64;
            float tv2 = 0.f, yv2 = 0.f;
            bool has2 = (c2 < 85);
            if (has2) { tv2 = tp[c2]; yv2 = yp[c2]; }    // ch 64..84

            float tw = __shfl(tv1, 2, 64);
            float th = __shfl(tv1, 3, 64);
            float bs = 2.0f - tw * th;

            float term;
            if (lane == 0)      term = bs * bce_f(tv1 * (float)g - (float)j, yv1);
            else if (lane == 1) term = bs * bce_f(tv1 * (float)g - (float)i, yv1);
            else if (lane == 2) { float d = logf(tv1 * 320.0f / aw) - yv1; term = bs * 0.5f * d * d; }
            else if (lane == 3) { float d = logf(tv1 * 320.0f / ah) - yv1; term = bs * 0.5f * d * d; }
            else if (lane == 4) term = 0.0f;             // conf for positives is in the neg path (gate=1)
            else                term = bce_f(tv1, yv1);  // cls 5..63
            if (has2) term += bce_f(tv2, yv2);           // cls 64..84
            acc += term;
        }
    }

    // wave64 reduce, one partials write per block (block = 1 wave)
    float v = acc;
    #pragma unroll
    for (int o = 32; o > 0; o >>= 1) v += __shfl_down(v, o, 64);
    if (threadIdx.x == 0) partials[blk] = v * 0.25f;   // mean over B=4
}

__global__ __launch_bounds__(256) void k_fin(
    const float* __restrict__ partials, float* __restrict__ out)
{
    float s = 0.0f;
    for (int i = threadIdx.x; i < NBLK; i += 256) s += partials[i];
    #pragma unroll
    for (int o = 32; o > 0; o >>= 1) s += __shfl_down(s, o, 64);
    __shared__ float red[4];
    int lane = threadIdx.x & 63, w = threadIdx.x >> 6;
    if (lane == 0) red[w] = s;
    __syncthreads();
    if (threadIdx.x == 0) out[0] = (red[0] + red[1]) + (red[2] + red[3]);
}

extern "C" void kernel_launch(void* const* d_in, const int* in_sizes, int n_in,
                              void* d_out, int out_size, void* d_ws, size_t ws_size,
                              hipStream_t stream) {
    // setup_inputs dict order: t0, y0, t1, y1, t2, y2
    const float* t0 = (const float*)d_in[0];
    const float* y0 = (const float*)d_in[1];
    const float* t1 = (const float*)d_in[2];
    const float* y1 = (const float*)d_in[3];
    const float* t2 = (const float*)d_in[4];
    const float* y2 = (const float*)d_in[5];

    int*    counts   = (int*)d_ws;
    float4* boxes    = (float4*)((char*)d_ws + 64);
    int*    posIdx   = (int*)((char*)d_ws + 43072);
    float*  partials = (float*)((char*)d_ws + 51264);
    float*  out      = (float*)d_out;

    k_init<<<1, 64, 0, stream>>>(counts);
    k_compact<<<394, 64, 0, stream>>>(t0, t1, t2, counts, boxes, posIdx);
    k_main<<<NBLK, 64, 0, stream>>>(t0, y0, t1, y1, t2, y2, counts, boxes, posIdx, partials);
    k_fin<<<1, 256, 0, stream>>>(partials, out);
}